// Round 20
// baseline (362.231 us; speedup 1.0000x reference)
//
#include <hip/hip_runtime.h>
#include <hip/hip_bf16.h>
#include <math.h>

using bf16x8 = __attribute__((ext_vector_type(8))) short;
using f32x4  = __attribute__((ext_vector_type(4))) float;

__device__ __forceinline__ float silu_f(float x) {
    float e = __expf(-x);
    float d = 1.f + e;
    return x * __builtin_amdgcn_rcpf(d);
}

// RNE f32->bf16 via compiler-generated v_cvt (m240: use casts, not inline asm)
__device__ __forceinline__ unsigned short f2bf(float x) {
    __hip_bfloat16 h = __float2bfloat16(x);
    return *reinterpret_cast<unsigned short*>(&h);
}
__device__ __forceinline__ unsigned f2bf2(float lo, float hi) {
    __hip_bfloat162 h2 = __float22bfloat162_rn(make_float2(lo, hi));
    return *reinterpret_cast<unsigned*>(&h2);
}
__device__ __forceinline__ float bf2f(unsigned short h) {
    union { unsigned u; float f; } v; v.u = ((unsigned)h) << 16;
    return v.f;
}

// ---------------- K1: node GEMM: sc = A@Wskip, xup = A@Wup, xdown = A@Wdown ----
__global__ __launch_bounds__(256) void k_node_gemm(
    const float* __restrict__ A,
    const float* __restrict__ Wskip, const float* __restrict__ Wup, const float* __restrict__ Wdown,
    float* __restrict__ sc, float* __restrict__ xup, float* __restrict__ xdown, int N)
{
    __shared__ float As[64][129];
    const int t = threadIdx.x;
    const int n0 = blockIdx.x * 64;
    for (int i = t; i < 64 * 32; i += 256) {
        int r = i >> 5, c4 = i & 31;
        int n = n0 + r;
        float4 v = make_float4(0.f, 0.f, 0.f, 0.f);
        if (n < N) v = ((const float4*)(A + (size_t)n * 128))[c4];
        As[r][c4 * 4 + 0] = v.x; As[r][c4 * 4 + 1] = v.y;
        As[r][c4 * 4 + 2] = v.z; As[r][c4 * 4 + 3] = v.w;
    }
    __syncthreads();
    const int tc = t & 15, tr = t >> 4;
    const int col0 = blockIdx.y * 64 + tc * 4;
    const float* W; float* dst; int ldw, wc, ldd;
    if (col0 < 128)      { W = Wskip; ldw = 128; wc = col0;       dst = sc;    ldd = 128; }
    else if (col0 < 256) { W = Wup;   ldw = 128; wc = col0 - 128; dst = xup;   ldd = 128; }
    else                 { W = Wdown; ldw = 64;  wc = col0 - 256; dst = xdown; ldd = 64;  }
    float acc[4][4] = {};
    for (int k = 0; k < 128; k++) {
        float4 wv = *(const float4*)(W + (size_t)k * ldw + wc);
        float wvv[4] = {wv.x, wv.y, wv.z, wv.w};
        float av[4];
        #pragma unroll
        for (int ii = 0; ii < 4; ii++) av[ii] = As[tr * 4 + ii][k];
        #pragma unroll
        for (int ii = 0; ii < 4; ii++)
            #pragma unroll
            for (int jj = 0; jj < 4; jj++)
                acc[ii][jj] = fmaf(av[ii], wvv[jj], acc[ii][jj]);
    }
    #pragma unroll
    for (int ii = 0; ii < 4; ii++) {
        int n = n0 + tr * 4 + ii;
        if (n < N)
            *(float4*)(dst + (size_t)n * ldd + wc) =
                make_float4(acc[ii][0], acc[ii][1], acc[ii][2], acc[ii][3]);
    }
}

// ---------------- weight prep: fold scale, transpose to [n][k], bf16, pad K ----
__global__ __launch_bounds__(256) void k_prep_w(
    const float* __restrict__ W, unsigned short* __restrict__ Wt,
    int Kin, int Kpad, int Nout, float scale)
{
    int i = blockIdx.x * 256 + threadIdx.x;
    if (i >= Nout * Kpad) return;
    int n = i / Kpad, k = i - n * Kpad;
    float v = (k < Kin) ? W[(size_t)k * Nout + n] * scale : 0.f;
    Wt[i] = f2bf(v);
}

// ---------------- K2: edge MLP via bf16 MFMA -> tp_w ---------------------------
#define MEB 128

__global__ __launch_bounds__(512, 2) void k_mlp_mfma(
    const float* __restrict__ ef, const int* __restrict__ eidx,
    const float* __restrict__ xdown,
    const unsigned short* __restrict__ Wt0, const unsigned short* __restrict__ Wt1,
    const unsigned short* __restrict__ Wt2, const unsigned short* __restrict__ Wt3,
    unsigned short* __restrict__ tp_w, int E, int eLo, int eHi)
{
    __shared__ unsigned short bufA[MEB][264];
    __shared__ unsigned short bufB[MEB][264];
    __shared__ int sE[MEB], rE[MEB];
    const int t = threadIdx.x;
    const int w = t >> 6, lane = t & 63;
    const int rA = lane & 15;
    const int kb = (lane >> 4) * 8;
    const int r0 = (lane >> 4) * 4;
    const int e0 = eLo + blockIdx.x * MEB;

    bf16x8 bw[16];
    f32x4 acc[8][2];

#define LOADW(WT, KPADW, NKS)                                                     \
    _Pragma("unroll")                                                             \
    for (int ks = 0; ks < NKS; ks++)                                              \
        _Pragma("unroll")                                                         \
        for (int nt = 0; nt < 2; nt++)                                            \
            bw[ks * 2 + nt] = *(const bf16x8*)&(WT)[(size_t)(w * 32 + nt * 16 + rA) * (KPADW) + ks * 32 + kb];

#define LMFMA(IN, NKS)                                                            \
    _Pragma("unroll")                                                             \
    for (int mt = 0; mt < 8; mt++)                                                \
        _Pragma("unroll")                                                         \
        for (int nt = 0; nt < 2; nt++)                                            \
            acc[mt][nt] = (f32x4){0.f, 0.f, 0.f, 0.f};                            \
    _Pragma("unroll")                                                             \
    for (int ks = 0; ks < NKS; ks++) {                                            \
        const int kk = ks * 32 + kb;                                              \
        bf16x8 afr[8];                                                            \
        _Pragma("unroll")                                                         \
        for (int mt = 0; mt < 8; mt++)                                            \
            afr[mt] = *(const bf16x8*)&IN[mt * 16 + rA][kk];                      \
        _Pragma("unroll")                                                         \
        for (int mt = 0; mt < 8; mt++)                                            \
            _Pragma("unroll")                                                     \
            for (int nt = 0; nt < 2; nt++)                                        \
                acc[mt][nt] = __builtin_amdgcn_mfma_f32_16x16x32_bf16(afr[mt], bw[ks * 2 + nt], acc[mt][nt], 0, 0, 0); \
    }

#define EPILOG(OUT, DOSILU)                                                       \
    _Pragma("unroll")                                                             \
    for (int mt = 0; mt < 8; mt++)                                                \
        _Pragma("unroll")                                                         \
        for (int nt = 0; nt < 2; nt++) {                                          \
            const int col = w * 32 + nt * 16 + rA;                                \
            _Pragma("unroll")                                                     \
            for (int r = 0; r < 4; r++) {                                         \
                float x = acc[mt][nt][r];                                         \
                if (DOSILU) x = silu_f(x);                                        \
                OUT[mt * 16 + r0 + r][col] = f2bf(x);                             \
            }                                                                     \
        }

    if (t < MEB) {
        int e = e0 + t; if (e >= E) e = E - 1;
        sE[t] = eidx[e]; rE[t] = eidx[E + e];
    }
    __syncthreads();
    // zero K-pad cols 136..159
    for (int i = t; i < MEB * 24; i += 512) {
        int r = i / 24, c = 136 + i % 24;
        bufA[r][c] = 0;
    }
    // stage aug = [ef(8) | xdown[s](64) | xdown[r](64)] as bf16
    for (int i = t; i < MEB * 34; i += 512) {
        int e = i / 34, j = i - e * 34;
        float4 v;
        if (j < 2) { int ee = e0 + e; if (ee >= E) ee = E - 1; v = ((const float4*)(ef + (size_t)ee * 8))[j]; }
        else if (j < 18) v = ((const float4*)(xdown + (size_t)sE[e] * 64))[j - 2];
        else             v = ((const float4*)(xdown + (size_t)rE[e] * 64))[j - 18];
        unsigned lo = f2bf2(v.x, v.y), hi = f2bf2(v.z, v.w);
        *(uint2*)&bufA[e][j * 4] = make_uint2(lo, hi);
    }
    __syncthreads();

    // L0: 136(pad160) -> 256, silu
    LOADW(Wt0, 160, 5)
    LMFMA(bufA, 5)
    EPILOG(bufB, true)
    __syncthreads();

    // L1: 256 -> 256, silu
    LOADW(Wt1, 256, 8)
    LMFMA(bufB, 8)
    EPILOG(bufA, true)
    __syncthreads();

    // L2: 256 -> 256, silu
    LOADW(Wt2, 256, 8)
    LMFMA(bufA, 8)
    EPILOG(bufB, true)
    __syncthreads();

    // L3 first half: 256 -> 256 (tp_w cols 0..255)
    LOADW(Wt3, 256, 8)
    LMFMA(bufB, 8)
    EPILOG(bufA, false)
    __syncthreads();
    for (int i = t; i < MEB * 64; i += 512) {
        int r = i >> 6, c4 = i & 63;
        int ee = e0 + r;
        if (ee < eHi) {
            ushort4 hv = *(ushort4*)&bufA[r][c4 * 4];
            *(ushort4*)&tp_w[(size_t)(ee - eLo) * 512 + c4 * 4] = hv;
        }
    }
    __syncthreads();

    // L3 second half: 256 -> 256 (tp_w cols 256..511)
    LOADW(Wt3 + (size_t)256 * 256, 256, 8)
    LMFMA(bufB, 8)
    EPILOG(bufA, false)
    __syncthreads();
    for (int i = t; i < MEB * 64; i += 512) {
        int r = i >> 6, c4 = i & 63;
        int ee = e0 + r;
        if (ee < eHi) {
            ushort4 hv = *(ushort4*)&bufA[r][c4 * 4];
            *(ushort4*)&tp_w[(size_t)(ee - eLo) * 512 + 256 + c4 * 4] = hv;
        }
    }
#undef LOADW
#undef LMFMA
#undef EPILOG
}

// ---------------- k_zx: u = tp_w * xup[sender]; z = u @ WoT[l]^T (in place) ----
__global__ __launch_bounds__(256, 2) void k_zx(
    unsigned short* __restrict__ tpw, const int* __restrict__ eidx,
    const float* __restrict__ xup, const unsigned short* __restrict__ WoT,
    int E, int eLo, int eHi)
{
    __shared__ __align__(16) unsigned short As[128 * 128];
    __shared__ __align__(16) unsigned short Bs[128 * 128];
    const int t = threadIdx.x;
    const int m0 = blockIdx.x * 128;
    const int l  = blockIdx.y;
    const int nE = eHi - eLo;

    #pragma unroll
    for (int i = 0; i < 8; i++) {
        int idx = i * 256 + t;
        int r = idx >> 4, cc = idx & 15;
        int el = m0 + r;
        int ecl = el < nE ? el : nE - 1;
        int s = eidx[eLo + ecl];
        uint4 tv = *(const uint4*)(tpw + (size_t)ecl * 512 + l * 128 + (cc << 3));
        float4 x0 = *(const float4*)(xup + (size_t)s * 128 + (cc << 3));
        float4 x1 = *(const float4*)(xup + (size_t)s * 128 + (cc << 3) + 4);
        const unsigned short* hp = (const unsigned short*)&tv;
        uint4 ov;
        unsigned* op = (unsigned*)&ov;
        op[0] = f2bf2(bf2f(hp[0]) * x0.x, bf2f(hp[1]) * x0.y);
        op[1] = f2bf2(bf2f(hp[2]) * x0.z, bf2f(hp[3]) * x0.w);
        op[2] = f2bf2(bf2f(hp[4]) * x1.x, bf2f(hp[5]) * x1.y);
        op[3] = f2bf2(bf2f(hp[6]) * x1.z, bf2f(hp[7]) * x1.w);
        *(uint4*)(&As[r * 128 + ((cc ^ (r & 7)) << 3)]) = ov;
    }
    #pragma unroll
    for (int i = 0; i < 8; i++) {
        int idx = i * 256 + t;
        int r = idx >> 4, cc = idx & 15;
        uint4 bv = *(const uint4*)(WoT + ((size_t)l * 128 + r) * 128 + (cc << 3));
        *(uint4*)(&Bs[r * 128 + ((cc ^ (r & 7)) << 3)]) = bv;
    }
    __syncthreads();

    const int lane = t & 63, rA = lane & 15, q = lane >> 4;
    const int wm = (t >> 6) & 1, wn = (t >> 6) >> 1;
    f32x4 acc[4][4];
    #pragma unroll
    for (int mt = 0; mt < 4; mt++)
        #pragma unroll
        for (int nt = 0; nt < 4; nt++)
            acc[mt][nt] = (f32x4){0.f, 0.f, 0.f, 0.f};

    #pragma unroll
    for (int ks = 0; ks < 4; ks++) {
        const int cc = ks * 4 + q;
        bf16x8 af[4], bfr[4];
        #pragma unroll
        for (int mt = 0; mt < 4; mt++) {
            int row = wm * 64 + mt * 16 + rA;
            af[mt] = *(const bf16x8*)&As[row * 128 + ((cc ^ (row & 7)) << 3)];
        }
        #pragma unroll
        for (int nt = 0; nt < 4; nt++) {
            int row = wn * 64 + nt * 16 + rA;
            bfr[nt] = *(const bf16x8*)&Bs[row * 128 + ((cc ^ (row & 7)) << 3)];
        }
        #pragma unroll
        for (int mt = 0; mt < 4; mt++)
            #pragma unroll
            for (int nt = 0; nt < 4; nt++)
                acc[mt][nt] = __builtin_amdgcn_mfma_f32_16x16x32_bf16(af[mt], bfr[nt], acc[mt][nt], 0, 0, 0);
    }
    __syncthreads();

    #pragma unroll
    for (int mt = 0; mt < 4; mt++) {
        #pragma unroll
        for (int r = 0; r < 4; r++) {
            int row = m0 + wm * 64 + mt * 16 + q * 4 + r;
            if (row >= nE) continue;
            #pragma unroll
            for (int nt = 0; nt < 4; nt++) {
                int col = wn * 64 + nt * 16 + rA;
                tpw[(size_t)row * 512 + l * 128 + col] = f2bf(acc[mt][nt][r]);
            }
        }
    }
}

// ---------------- CSR construction --------------------------------------------
__global__ __launch_bounds__(256) void k_hist(const int* __restrict__ recv, int* __restrict__ deg, int E)
{
    int e = blockIdx.x * 256 + threadIdx.x;
    if (e < E) atomicAdd(&deg[recv[e]], 1);
}

__global__ __launch_bounds__(1024) void k_scan(const int* __restrict__ deg, int* __restrict__ rowptr, int N)
{
    __shared__ int sdata[1024];
    __shared__ int carry;
    const int t = threadIdx.x;
    if (t == 0) carry = 0;
    __syncthreads();
    for (int base = 0; base < N; base += 1024) {
        int i = base + t;
        int v = (i < N) ? deg[i] : 0;
        sdata[t] = v;
        __syncthreads();
        for (int off = 1; off < 1024; off <<= 1) {
            int x = (t >= off) ? sdata[t - off] : 0;
            __syncthreads();
            sdata[t] += x;
            __syncthreads();
        }
        if (i < N) rowptr[i] = carry + sdata[t] - v;
        __syncthreads();
        if (t == 0) carry += sdata[1023];
        __syncthreads();
    }
    if (t == 0) rowptr[N] = carry;
}

__global__ __launch_bounds__(256) void k_scatter(const int* __restrict__ recv,
    const int* __restrict__ rowptr, int* __restrict__ fill, int* __restrict__ perm, int E)
{
    int e = blockIdx.x * 256 + threadIdx.x;
    if (e < E) {
        int r = recv[e];
        int pos = rowptr[r] + atomicAdd(&fill[r], 1);
        perm[pos] = e;
    }
}

__global__ __launch_bounds__(256) void k_sortlists(int* __restrict__ perm, const int* __restrict__ rowptr, int N)
{
    int n = blockIdx.x * 256 + threadIdx.x;
    if (n >= N) return;
    int lo = rowptr[n], hi = rowptr[n + 1];
    for (int i = lo + 1; i < hi; i++) {
        int key = perm[i];
        int j = i - 1;
        while (j >= lo && perm[j] > key) { perm[j + 1] = perm[j]; j--; }
        perm[j + 1] = key;
    }
}

// ---------------- K3: per-node gather, padded batches + pipelined staging ------
__global__ __launch_bounds__(64) void k_gather(
    const unsigned short* __restrict__ z, const float* __restrict__ ea,
    const int* __restrict__ perm, const int* __restrict__ rowptr,
    float* __restrict__ outb, int E, int eLo, int eHi, int storeMode)
{
    const int n = blockIdx.x;
    const int lo = rowptr[n], hi = rowptr[n + 1];
    const int t = threadIdx.x;           // lane 0..63; covers c = t and c = t+64
    const int nE = eHi - eLo;
    constexpr float CG1 = 0.57735026919f, CG2 = 0.44721359550f, CG3 = 0.37796447301f;
    float acc[2][2][8] = {};             // [ci][half][8]
    __shared__ int eG[68];
    __shared__ int eL[68];
    __shared__ float yL[68][17];
    __shared__ __align__(16) unsigned short zb[4][512];

    const int sle = t >> 4;              // staging: edge-in-batch 0..3
    const int sch = t & 15;              // staging: chunk group 0..15

    for (int base = lo; base < hi; base += 64) {
        int cnt = min(64, hi - base);
        int cntp = (cnt + 3) & ~3;       // pad to multiple of 4
        __syncthreads();
        for (int i = t; i < cnt; i += 64) {
            int e = perm[base + i];
            eG[i] = e;
            int el = e - eLo;
            eL[i] = (el >= 0 && el < nE) ? el : 0;
        }
        if (t < 4 && cnt + t < cntp) eL[cnt + t] = 0;   // pad rows -> z row 0
        __syncthreads();
        for (int i = t; i < cntp * 16; i += 64) {
            int el = i >> 4, m = i & 15;
            float v = 0.f;
            if (el < cnt) {
                int e = eG[el];
                float vv = ea[(size_t)e * 16 + m];
                v = (e >= eLo && e < eHi) ? vv : 0.f;
            }
            yL[el][m] = v;
        }
        __syncthreads();

        // pipelined batches of 4: issue next batch's loads while computing
        uint4 rz[4];
        {
            const unsigned short* zz = z + (size_t)eL[sle] * 512;
            #pragma unroll
            for (int i = 0; i < 4; i++)
                rz[i] = *(const uint4*)(zz + (sch + 16 * i) * 8);
        }
        for (int j = 0; j < cntp; j += 4) {
            #pragma unroll
            for (int i = 0; i < 4; i++)
                *(uint4*)&zb[sle][(sch + 16 * i) * 8] = rz[i];
            __syncthreads();
            if (j + 4 < cntp) {
                const unsigned short* zz = z + (size_t)eL[j + 4 + sle] * 512;
                #pragma unroll
                for (int i = 0; i < 4; i++)
                    rz[i] = *(const uint4*)(zz + (sch + 16 * i) * 8);
            }
            #pragma unroll
            for (int k = 0; k < 4; k++) {
                const float* y = yL[j + k];
                const unsigned short* zr = zb[k];
                #pragma unroll
                for (int ci = 0; ci < 2; ci++) {
                    int c = t + ci * 64;
                    float z0 = bf2f(zr[c]);
                    float z1 = bf2f(zr[128 + c]) * CG1;
                    float z2 = bf2f(zr[256 + c]) * CG2;
                    float z3 = bf2f(zr[384 + c]) * CG3;
                    acc[ci][0][0] = fmaf(z0, y[0], acc[ci][0][0]);
                    #pragma unroll
                    for (int m = 0; m < 3; m++) acc[ci][0][1 + m] = fmaf(z1, y[1 + m], acc[ci][0][1 + m]);
                    #pragma unroll
                    for (int m = 0; m < 4; m++) acc[ci][0][4 + m] = fmaf(z2, y[4 + m], acc[ci][0][4 + m]);
                    acc[ci][1][0] = fmaf(z2, y[8], acc[ci][1][0]);
                    #pragma unroll
                    for (int m = 0; m < 7; m++) acc[ci][1][1 + m] = fmaf(z3, y[9 + m], acc[ci][1][1 + m]);
                }
            }
            __syncthreads();
        }
    }

    #pragma unroll
    for (int ci = 0; ci < 2; ci++) {
        float* orow = outb + (size_t)n * 2048 + (size_t)(t + ci * 64) * 16;
        if (storeMode) {
            *(float4*)(orow)      = make_float4(acc[ci][0][0], acc[ci][0][1], acc[ci][0][2], acc[ci][0][3]);
            *(float4*)(orow + 4)  = make_float4(acc[ci][0][4], acc[ci][0][5], acc[ci][0][6], acc[ci][0][7]);
            *(float4*)(orow + 8)  = make_float4(acc[ci][1][0], acc[ci][1][1], acc[ci][1][2], acc[ci][1][3]);
            *(float4*)(orow + 12) = make_float4(acc[ci][1][4], acc[ci][1][5], acc[ci][1][6], acc[ci][1][7]);
        } else {
            float4 a = *(float4*)(orow), b = *(float4*)(orow + 4);
            float4 cc = *(float4*)(orow + 8), d = *(float4*)(orow + 12);
            a.x += acc[ci][0][0]; a.y += acc[ci][0][1]; a.z += acc[ci][0][2]; a.w += acc[ci][0][3];
            b.x += acc[ci][0][4]; b.y += acc[ci][0][5]; b.z += acc[ci][0][6]; b.w += acc[ci][0][7];
            cc.x += acc[ci][1][0]; cc.y += acc[ci][1][1]; cc.z += acc[ci][1][2]; cc.w += acc[ci][1][3];
            d.x += acc[ci][1][4]; d.y += acc[ci][1][5]; d.z += acc[ci][1][6]; d.w += acc[ci][1][7];
            *(float4*)(orow) = a; *(float4*)(orow + 4) = b;
            *(float4*)(orow + 8) = cc; *(float4*)(orow + 12) = d;
        }
    }
}

extern "C" void kernel_launch(void* const* d_in, const int* in_sizes, int n_in,
                              void* d_out, int out_size, void* d_ws, size_t ws_size,
                              hipStream_t stream)
{
    const float* node_feats = (const float*)d_in[1];
    const float* edge_attrs = (const float*)d_in[2];
    const float* edge_feats = (const float*)d_in[3];
    const int*   edge_index = (const int*)d_in[4];
    const float* W_up   = (const float*)d_in[5];
    const float* W_down = (const float*)d_in[6];
    const float* W_skip = (const float*)d_in[7];
    const float* W_fc0  = (const float*)d_in[8];
    const float* W_fc1  = (const float*)d_in[9];
    const float* W_fc2  = (const float*)d_in[10];
    const float* W_fc3  = (const float*)d_in[11];
    const float* W_out  = (const float*)d_in[12];
    const int N = in_sizes[1] / 128;
    const int E = in_sizes[3] / 8;

    float* out = (float*)d_out;
    float* sc  = out + (size_t)N * 2048;

    // workspace layout
    float* xup   = (float*)d_ws;
    float* xdown = xup + (size_t)N * 128;
    int* deg    = (int*)(xdown + (size_t)N * 64);
    int* fill   = deg + N;
    int* rowptr = fill + N;
    int* perm   = rowptr + N + 1;
    size_t used = (size_t)((char*)(perm + E) - (char*)d_ws);
    used = (used + 255) & ~(size_t)255;
    unsigned short* Wt0 = (unsigned short*)((char*)d_ws + used);  // 256 x 160
    unsigned short* Wt1 = Wt0 + 256 * 160;                        // 256 x 256
    unsigned short* Wt2 = Wt1 + 256 * 256;
    unsigned short* Wt3 = Wt2 + 256 * 256;                        // 512 x 256
    unsigned short* WoT = Wt3 + 512 * 256;                        // 4 x 128 x 128
    used = (size_t)((char*)(WoT + 4 * 128 * 128) - (char*)d_ws);
    used = (used + 255) & ~(size_t)255;
    unsigned short* tpw = (unsigned short*)((char*)d_ws + used);  // Ec x 512 (tp_w -> z in place)
    size_t avail = (ws_size > used) ? ws_size - used : 0;
    long long Ec_l = (long long)(avail / (512 * sizeof(unsigned short)));
    int Ec = (int)(Ec_l > E ? E : Ec_l);
    if (Ec < 8) Ec = 8;
    const int nchunks = (E + Ec - 1) / Ec;

    hipMemsetAsync(deg, 0, (size_t)2 * N * sizeof(int), stream);
    if (nchunks > 1)
        hipMemsetAsync(out, 0, (size_t)N * 2048 * sizeof(float), stream);

    dim3 g1((N + 63) / 64, 5);
    k_node_gemm<<<g1, 256, 0, stream>>>(node_feats, W_skip, W_up, W_down, sc, xup, xdown, N);

    constexpr float S0 = 0.085749292571254f; // 1/sqrt(136)
    k_prep_w<<<(256 * 160 + 255) / 256, 256, 0, stream>>>(W_fc0, Wt0, 136, 160, 256, S0);
    k_prep_w<<<(256 * 256 + 255) / 256, 256, 0, stream>>>(W_fc1, Wt1, 256, 256, 256, 0.0625f);
    k_prep_w<<<(256 * 256 + 255) / 256, 256, 0, stream>>>(W_fc2, Wt2, 256, 256, 256, 0.0625f);
    k_prep_w<<<(512 * 256 + 255) / 256, 256, 0, stream>>>(W_fc3, Wt3, 256, 256, 512, 0.0625f);
    for (int l = 0; l < 4; l++)
        k_prep_w<<<(128 * 128 + 255) / 256, 256, 0, stream>>>(W_out + (size_t)l * 16384,
                                                              WoT + (size_t)l * 16384,
                                                              128, 128, 128, 0.1f);

    const int* recv = edge_index + E;
    k_hist<<<(E + 255) / 256, 256, 0, stream>>>(recv, deg, E);
    k_scan<<<1, 1024, 0, stream>>>(deg, rowptr, N);
    k_scatter<<<(E + 255) / 256, 256, 0, stream>>>(recv, rowptr, fill, perm, E);
    k_sortlists<<<(N + 255) / 256, 256, 0, stream>>>(perm, rowptr, N);

    for (int ch = 0; ch < nchunks; ch++) {
        int eLo = ch * Ec;
        int eHi = eLo + Ec; if (eHi > E) eHi = E;
        int nE = eHi - eLo;

        k_mlp_mfma<<<(nE + MEB - 1) / MEB, 512, 0, stream>>>(edge_feats, edge_index, xdown,
                                                             Wt0, Wt1, Wt2, Wt3,
                                                             tpw, E, eLo, eHi);
        k_zx<<<dim3((nE + 127) / 128, 4), 256, 0, stream>>>(tpw, edge_index, xup, WoT,
                                                            E, eLo, eHi);
        k_gather<<<N, 64, 0, stream>>>(tpw, edge_attrs, perm, rowptr,
                                       out, E, eLo, eHi, nchunks == 1 ? 1 : 0);
    }
}

// Round 21
// 345.425 us; speedup vs baseline: 1.0487x; 1.0487x over previous
//
#include <hip/hip_runtime.h>
#include <hip/hip_bf16.h>
#include <math.h>

using bf16x8 = __attribute__((ext_vector_type(8))) short;
using f32x4  = __attribute__((ext_vector_type(4))) float;

__device__ __forceinline__ float silu_f(float x) {
    float e = __expf(-x);
    float d = 1.f + e;
    return x * __builtin_amdgcn_rcpf(d);
}

// RNE f32->bf16 via compiler-generated v_cvt (m240: use casts, not inline asm)
__device__ __forceinline__ unsigned short f2bf(float x) {
    __hip_bfloat16 h = __float2bfloat16(x);
    return *reinterpret_cast<unsigned short*>(&h);
}
__device__ __forceinline__ unsigned f2bf2(float lo, float hi) {
    __hip_bfloat162 h2 = __float22bfloat162_rn(make_float2(lo, hi));
    return *reinterpret_cast<unsigned*>(&h2);
}
__device__ __forceinline__ float bf2f(unsigned short h) {
    union { unsigned u; float f; } v; v.u = ((unsigned)h) << 16;
    return v.f;
}

// ---------------- K1: node GEMM: sc = A@Wskip, xup = A@Wup, xdown = A@Wdown ----
__global__ __launch_bounds__(256) void k_node_gemm(
    const float* __restrict__ A,
    const float* __restrict__ Wskip, const float* __restrict__ Wup, const float* __restrict__ Wdown,
    float* __restrict__ sc, float* __restrict__ xup, float* __restrict__ xdown, int N)
{
    __shared__ float As[64][129];
    const int t = threadIdx.x;
    const int n0 = blockIdx.x * 64;
    for (int i = t; i < 64 * 32; i += 256) {
        int r = i >> 5, c4 = i & 31;
        int n = n0 + r;
        float4 v = make_float4(0.f, 0.f, 0.f, 0.f);
        if (n < N) v = ((const float4*)(A + (size_t)n * 128))[c4];
        As[r][c4 * 4 + 0] = v.x; As[r][c4 * 4 + 1] = v.y;
        As[r][c4 * 4 + 2] = v.z; As[r][c4 * 4 + 3] = v.w;
    }
    __syncthreads();
    const int tc = t & 15, tr = t >> 4;
    const int col0 = blockIdx.y * 64 + tc * 4;
    const float* W; float* dst; int ldw, wc, ldd;
    if (col0 < 128)      { W = Wskip; ldw = 128; wc = col0;       dst = sc;    ldd = 128; }
    else if (col0 < 256) { W = Wup;   ldw = 128; wc = col0 - 128; dst = xup;   ldd = 128; }
    else                 { W = Wdown; ldw = 64;  wc = col0 - 256; dst = xdown; ldd = 64;  }
    float acc[4][4] = {};
    for (int k = 0; k < 128; k++) {
        float4 wv = *(const float4*)(W + (size_t)k * ldw + wc);
        float wvv[4] = {wv.x, wv.y, wv.z, wv.w};
        float av[4];
        #pragma unroll
        for (int ii = 0; ii < 4; ii++) av[ii] = As[tr * 4 + ii][k];
        #pragma unroll
        for (int ii = 0; ii < 4; ii++)
            #pragma unroll
            for (int jj = 0; jj < 4; jj++)
                acc[ii][jj] = fmaf(av[ii], wvv[jj], acc[ii][jj]);
    }
    #pragma unroll
    for (int ii = 0; ii < 4; ii++) {
        int n = n0 + tr * 4 + ii;
        if (n < N)
            *(float4*)(dst + (size_t)n * ldd + wc) =
                make_float4(acc[ii][0], acc[ii][1], acc[ii][2], acc[ii][3]);
    }
}

// ---------------- weight prep: fold scale, transpose to [n][k], bf16, pad K ----
__global__ __launch_bounds__(256) void k_prep_w(
    const float* __restrict__ W, unsigned short* __restrict__ Wt,
    int Kin, int Kpad, int Nout, float scale)
{
    int i = blockIdx.x * 256 + threadIdx.x;
    if (i >= Nout * Kpad) return;
    int n = i / Kpad, k = i - n * Kpad;
    float v = (k < Kin) ? W[(size_t)k * Nout + n] * scale : 0.f;
    Wt[i] = f2bf(v);
}

// ---------------- K2: edge MLP via bf16 MFMA -> tp_w ---------------------------
// Single LDS buffer (in-place layers) -> 68.6 KB -> 2 blocks/CU, 4 waves/SIMD.
// L3 halves read unchanged L2-output and store acc directly to global.
#define MEB 128

__global__ __launch_bounds__(512, 2) void k_mlp_mfma(
    const float* __restrict__ ef, const int* __restrict__ eidx,
    const float* __restrict__ xdown,
    const unsigned short* __restrict__ Wt0, const unsigned short* __restrict__ Wt1,
    const unsigned short* __restrict__ Wt2, const unsigned short* __restrict__ Wt3,
    unsigned short* __restrict__ tp_w, int E, int eLo, int eHi)
{
    __shared__ unsigned short buf[MEB][264];
    __shared__ int sE[MEB], rE[MEB];
    const int t = threadIdx.x;
    const int w = t >> 6, lane = t & 63;
    const int rA = lane & 15;
    const int kb = (lane >> 4) * 8;
    const int r0 = (lane >> 4) * 4;
    const int e0 = eLo + blockIdx.x * MEB;

    bf16x8 bw[16];
    f32x4 acc[8][2];

#define LOADW(WT, KPADW, NKS)                                                     \
    _Pragma("unroll")                                                             \
    for (int ks = 0; ks < NKS; ks++)                                              \
        _Pragma("unroll")                                                         \
        for (int nt = 0; nt < 2; nt++)                                            \
            bw[ks * 2 + nt] = *(const bf16x8*)&(WT)[(size_t)(w * 32 + nt * 16 + rA) * (KPADW) + ks * 32 + kb];

#define LMFMA(IN, NKS)                                                            \
    _Pragma("unroll")                                                             \
    for (int mt = 0; mt < 8; mt++)                                                \
        _Pragma("unroll")                                                         \
        for (int nt = 0; nt < 2; nt++)                                            \
            acc[mt][nt] = (f32x4){0.f, 0.f, 0.f, 0.f};                            \
    _Pragma("unroll")                                                             \
    for (int ks = 0; ks < NKS; ks++) {                                            \
        const int kk = ks * 32 + kb;                                              \
        bf16x8 afr[8];                                                            \
        _Pragma("unroll")                                                         \
        for (int mt = 0; mt < 8; mt++)                                            \
            afr[mt] = *(const bf16x8*)&IN[mt * 16 + rA][kk];                      \
        _Pragma("unroll")                                                         \
        for (int mt = 0; mt < 8; mt++)                                            \
            _Pragma("unroll")                                                     \
            for (int nt = 0; nt < 2; nt++)                                        \
                acc[mt][nt] = __builtin_amdgcn_mfma_f32_16x16x32_bf16(afr[mt], bw[ks * 2 + nt], acc[mt][nt], 0, 0, 0); \
    }

#define EPILOG(OUT, DOSILU)                                                       \
    _Pragma("unroll")                                                             \
    for (int mt = 0; mt < 8; mt++)                                                \
        _Pragma("unroll")                                                         \
        for (int nt = 0; nt < 2; nt++) {                                          \
            const int col = w * 32 + nt * 16 + rA;                                \
            _Pragma("unroll")                                                     \
            for (int r = 0; r < 4; r++) {                                         \
                float x = acc[mt][nt][r];                                         \
                if (DOSILU) x = silu_f(x);                                        \
                OUT[mt * 16 + r0 + r][col] = f2bf(x);                             \
            }                                                                     \
        }

// direct global store of acc as bf16 into tp_w cols [OFF, OFF+256)
#define STOREG(OFF)                                                               \
    _Pragma("unroll")                                                             \
    for (int mt = 0; mt < 8; mt++) {                                              \
        _Pragma("unroll")                                                         \
        for (int r = 0; r < 4; r++) {                                             \
            int ee = e0 + mt * 16 + r0 + r;                                       \
            if (ee < eHi) {                                                       \
                _Pragma("unroll")                                                 \
                for (int nt = 0; nt < 2; nt++)                                    \
                    tp_w[(size_t)(ee - eLo) * 512 + (OFF) + w * 32 + nt * 16 + rA] = f2bf(acc[mt][nt][r]); \
            }                                                                     \
        }                                                                         \
    }

    if (t < MEB) {
        int e = e0 + t; if (e >= E) e = E - 1;
        sE[t] = eidx[e]; rE[t] = eidx[E + e];
    }
    __syncthreads();
    // zero K-pad cols 136..159
    for (int i = t; i < MEB * 24; i += 512) {
        int r = i / 24, c = 136 + i % 24;
        buf[r][c] = 0;
    }
    // stage aug = [ef(8) | xdown[s](64) | xdown[r](64)] as bf16
    for (int i = t; i < MEB * 34; i += 512) {
        int e = i / 34, j = i - e * 34;
        float4 v;
        if (j < 2) { int ee = e0 + e; if (ee >= E) ee = E - 1; v = ((const float4*)(ef + (size_t)ee * 8))[j]; }
        else if (j < 18) v = ((const float4*)(xdown + (size_t)sE[e] * 64))[j - 2];
        else             v = ((const float4*)(xdown + (size_t)rE[e] * 64))[j - 18];
        unsigned lo = f2bf2(v.x, v.y), hi = f2bf2(v.z, v.w);
        *(uint2*)&buf[e][j * 4] = make_uint2(lo, hi);
    }
    __syncthreads();

    // L0: 136(pad160) -> 256, silu, in place
    LOADW(Wt0, 160, 5)
    LMFMA(buf, 5)
    __syncthreads();
    EPILOG(buf, true)
    __syncthreads();

    // L1: 256 -> 256, silu, in place
    LOADW(Wt1, 256, 8)
    LMFMA(buf, 8)
    __syncthreads();
    EPILOG(buf, true)
    __syncthreads();

    // L2: 256 -> 256, silu, in place
    LOADW(Wt2, 256, 8)
    LMFMA(buf, 8)
    __syncthreads();
    EPILOG(buf, true)
    __syncthreads();

    // L3 first half: read buf (unchanged), store direct to global
    LOADW(Wt3, 256, 8)
    LMFMA(buf, 8)
    STOREG(0)

    // L3 second half: buf still unchanged, no barrier needed
    LOADW(Wt3 + (size_t)256 * 256, 256, 8)
    LMFMA(buf, 8)
    STOREG(256)
#undef LOADW
#undef LMFMA
#undef EPILOG
#undef STOREG
}

// ---------------- k_zx: u = tp_w * xup[sender]; z = u @ WoT[l]^T (in place) ----
__global__ __launch_bounds__(256, 2) void k_zx(
    unsigned short* __restrict__ tpw, const int* __restrict__ eidx,
    const float* __restrict__ xup, const unsigned short* __restrict__ WoT,
    int E, int eLo, int eHi)
{
    __shared__ __align__(16) unsigned short As[128 * 128];
    __shared__ __align__(16) unsigned short Bs[128 * 128];
    const int t = threadIdx.x;
    const int m0 = blockIdx.x * 128;
    const int l  = blockIdx.y;
    const int nE = eHi - eLo;

    #pragma unroll
    for (int i = 0; i < 8; i++) {
        int idx = i * 256 + t;
        int r = idx >> 4, cc = idx & 15;
        int el = m0 + r;
        int ecl = el < nE ? el : nE - 1;
        int s = eidx[eLo + ecl];
        uint4 tv = *(const uint4*)(tpw + (size_t)ecl * 512 + l * 128 + (cc << 3));
        float4 x0 = *(const float4*)(xup + (size_t)s * 128 + (cc << 3));
        float4 x1 = *(const float4*)(xup + (size_t)s * 128 + (cc << 3) + 4);
        const unsigned short* hp = (const unsigned short*)&tv;
        uint4 ov;
        unsigned* op = (unsigned*)&ov;
        op[0] = f2bf2(bf2f(hp[0]) * x0.x, bf2f(hp[1]) * x0.y);
        op[1] = f2bf2(bf2f(hp[2]) * x0.z, bf2f(hp[3]) * x0.w);
        op[2] = f2bf2(bf2f(hp[4]) * x1.x, bf2f(hp[5]) * x1.y);
        op[3] = f2bf2(bf2f(hp[6]) * x1.z, bf2f(hp[7]) * x1.w);
        *(uint4*)(&As[r * 128 + ((cc ^ (r & 7)) << 3)]) = ov;
    }
    #pragma unroll
    for (int i = 0; i < 8; i++) {
        int idx = i * 256 + t;
        int r = idx >> 4, cc = idx & 15;
        uint4 bv = *(const uint4*)(WoT + ((size_t)l * 128 + r) * 128 + (cc << 3));
        *(uint4*)(&Bs[r * 128 + ((cc ^ (r & 7)) << 3)]) = bv;
    }
    __syncthreads();

    const int lane = t & 63, rA = lane & 15, q = lane >> 4;
    const int wm = (t >> 6) & 1, wn = (t >> 6) >> 1;
    f32x4 acc[4][4];
    #pragma unroll
    for (int mt = 0; mt < 4; mt++)
        #pragma unroll
        for (int nt = 0; nt < 4; nt++)
            acc[mt][nt] = (f32x4){0.f, 0.f, 0.f, 0.f};

    #pragma unroll
    for (int ks = 0; ks < 4; ks++) {
        const int cc = ks * 4 + q;
        bf16x8 af[4], bfr[4];
        #pragma unroll
        for (int mt = 0; mt < 4; mt++) {
            int row = wm * 64 + mt * 16 + rA;
            af[mt] = *(const bf16x8*)&As[row * 128 + ((cc ^ (row & 7)) << 3)];
        }
        #pragma unroll
        for (int nt = 0; nt < 4; nt++) {
            int row = wn * 64 + nt * 16 + rA;
            bfr[nt] = *(const bf16x8*)&Bs[row * 128 + ((cc ^ (row & 7)) << 3)];
        }
        #pragma unroll
        for (int mt = 0; mt < 4; mt++)
            #pragma unroll
            for (int nt = 0; nt < 4; nt++)
                acc[mt][nt] = __builtin_amdgcn_mfma_f32_16x16x32_bf16(af[mt], bfr[nt], acc[mt][nt], 0, 0, 0);
    }
    __syncthreads();

    #pragma unroll
    for (int mt = 0; mt < 4; mt++) {
        #pragma unroll
        for (int r = 0; r < 4; r++) {
            int row = m0 + wm * 64 + mt * 16 + q * 4 + r;
            if (row >= nE) continue;
            #pragma unroll
            for (int nt = 0; nt < 4; nt++) {
                int col = wn * 64 + nt * 16 + rA;
                tpw[(size_t)row * 512 + l * 128 + col] = f2bf(acc[mt][nt][r]);
            }
        }
    }
}

// ---------------- CSR construction --------------------------------------------
__global__ __launch_bounds__(256) void k_hist(const int* __restrict__ recv, int* __restrict__ deg, int E)
{
    int e = blockIdx.x * 256 + threadIdx.x;
    if (e < E) atomicAdd(&deg[recv[e]], 1);
}

__global__ __launch_bounds__(1024) void k_scan(const int* __restrict__ deg, int* __restrict__ rowptr, int N)
{
    __shared__ int sdata[1024];
    __shared__ int carry;
    const int t = threadIdx.x;
    if (t == 0) carry = 0;
    __syncthreads();
    for (int base = 0; base < N; base += 1024) {
        int i = base + t;
        int v = (i < N) ? deg[i] : 0;
        sdata[t] = v;
        __syncthreads();
        for (int off = 1; off < 1024; off <<= 1) {
            int x = (t >= off) ? sdata[t - off] : 0;
            __syncthreads();
            sdata[t] += x;
            __syncthreads();
        }
        if (i < N) rowptr[i] = carry + sdata[t] - v;
        __syncthreads();
        if (t == 0) carry += sdata[1023];
        __syncthreads();
    }
    if (t == 0) rowptr[N] = carry;
}

__global__ __launch_bounds__(256) void k_scatter(const int* __restrict__ recv,
    const int* __restrict__ rowptr, int* __restrict__ fill, int* __restrict__ perm, int E)
{
    int e = blockIdx.x * 256 + threadIdx.x;
    if (e < E) {
        int r = recv[e];
        int pos = rowptr[r] + atomicAdd(&fill[r], 1);
        perm[pos] = e;
    }
}

__global__ __launch_bounds__(256) void k_sortlists(int* __restrict__ perm, const int* __restrict__ rowptr, int N)
{
    int n = blockIdx.x * 256 + threadIdx.x;
    if (n >= N) return;
    int lo = rowptr[n], hi = rowptr[n + 1];
    for (int i = lo + 1; i < hi; i++) {
        int key = perm[i];
        int j = i - 1;
        while (j >= lo && perm[j] > key) { perm[j + 1] = perm[j]; j--; }
        perm[j + 1] = key;
    }
}

// ---------------- K3: per-node gather, LDS-staged coalesced z reads (R19) ------
__global__ __launch_bounds__(64) void k_gather(
    const unsigned short* __restrict__ z, const float* __restrict__ ea,
    const int* __restrict__ perm, const int* __restrict__ rowptr,
    float* __restrict__ outb, int E, int eLo, int eHi, int storeMode)
{
    const int n = blockIdx.x;
    const int lo = rowptr[n], hi = rowptr[n + 1];
    const int t = threadIdx.x;           // lane 0..63; covers c = t and c = t+64
    const int nE = eHi - eLo;
    constexpr float CG1 = 0.57735026919f, CG2 = 0.44721359550f, CG3 = 0.37796447301f;
    float acc[2][2][8] = {};             // [ci][half][8]
    __shared__ int eG[64];
    __shared__ int eL[64];
    __shared__ float yL[64][17];
    __shared__ __align__(16) unsigned short zb[4][512];

    const int sle = t >> 4;              // staging: edge-in-batch 0..3
    const int sch = t & 15;              // staging: chunk group 0..15

    for (int base = lo; base < hi; base += 64) {
        int cnt = min(64, hi - base);
        __syncthreads();
        for (int i = t; i < cnt; i += 64) {
            int e = perm[base + i];
            eG[i] = e;
            int el = e - eLo;
            eL[i] = (el >= 0 && el < nE) ? el : 0;
        }
        __syncthreads();
        for (int i = t; i < cnt * 16; i += 64) {
            int el = i >> 4, m = i & 15;
            int e = eG[el];
            float v = ea[(size_t)e * 16 + m];
            yL[el][m] = (e >= eLo && e < eHi) ? v : 0.f;
        }
        __syncthreads();

        int j = 0;
        for (; j + 4 <= cnt; j += 4) {
            const unsigned short* zz = z + (size_t)eL[j + sle] * 512;
            #pragma unroll
            for (int i = 0; i < 4; i++)
                *(uint4*)&zb[sle][(sch + 16 * i) * 8] = *(const uint4*)(zz + (sch + 16 * i) * 8);
            __syncthreads();
            #pragma unroll
            for (int k = 0; k < 4; k++) {
                const float* y = yL[j + k];
                const unsigned short* zr = zb[k];
                #pragma unroll
                for (int ci = 0; ci < 2; ci++) {
                    int c = t + ci * 64;
                    float z0 = bf2f(zr[c]);
                    float z1 = bf2f(zr[128 + c]) * CG1;
                    float z2 = bf2f(zr[256 + c]) * CG2;
                    float z3 = bf2f(zr[384 + c]) * CG3;
                    acc[ci][0][0] = fmaf(z0, y[0], acc[ci][0][0]);
                    #pragma unroll
                    for (int m = 0; m < 3; m++) acc[ci][0][1 + m] = fmaf(z1, y[1 + m], acc[ci][0][1 + m]);
                    #pragma unroll
                    for (int m = 0; m < 4; m++) acc[ci][0][4 + m] = fmaf(z2, y[4 + m], acc[ci][0][4 + m]);
                    acc[ci][1][0] = fmaf(z2, y[8], acc[ci][1][0]);
                    #pragma unroll
                    for (int m = 0; m < 7; m++) acc[ci][1][1 + m] = fmaf(z3, y[9 + m], acc[ci][1][1 + m]);
                }
            }
            __syncthreads();
        }
        for (; j < cnt; j++) {
            const unsigned short* zz = z + (size_t)eL[j] * 512;
            const float* y = yL[j];
            #pragma unroll
            for (int ci = 0; ci < 2; ci++) {
                int c = t + ci * 64;
                float z0 = bf2f(zz[c]);
                float z1 = bf2f(zz[128 + c]) * CG1;
                float z2 = bf2f(zz[256 + c]) * CG2;
                float z3 = bf2f(zz[384 + c]) * CG3;
                acc[ci][0][0] = fmaf(z0, y[0], acc[ci][0][0]);
                #pragma unroll
                for (int m = 0; m < 3; m++) acc[ci][0][1 + m] = fmaf(z1, y[1 + m], acc[ci][0][1 + m]);
                #pragma unroll
                for (int m = 0; m < 4; m++) acc[ci][0][4 + m] = fmaf(z2, y[4 + m], acc[ci][0][4 + m]);
                acc[ci][1][0] = fmaf(z2, y[8], acc[ci][1][0]);
                #pragma unroll
                for (int m = 0; m < 7; m++) acc[ci][1][1 + m] = fmaf(z3, y[9 + m], acc[ci][1][1 + m]);
            }
        }
    }

    #pragma unroll
    for (int ci = 0; ci < 2; ci++) {
        float* orow = outb + (size_t)n * 2048 + (size_t)(t + ci * 64) * 16;
        if (storeMode) {
            *(float4*)(orow)      = make_float4(acc[ci][0][0], acc[ci][0][1], acc[ci][0][2], acc[ci][0][3]);
            *(float4*)(orow + 4)  = make_float4(acc[ci][0][4], acc[ci][0][5], acc[ci][0][6], acc[ci][0][7]);
            *(float4*)(orow + 8)  = make_float4(acc[ci][1][0], acc[ci][1][1], acc[ci][1][2], acc[ci][1][3]);
            *(float4*)(orow + 12) = make_float4(acc[ci][1][4], acc[ci][1][5], acc[ci][1][6], acc[ci][1][7]);
        } else {
            float4 a = *(float4*)(orow), b = *(float4*)(orow + 4);
            float4 cc = *(float4*)(orow + 8), d = *(float4*)(orow + 12);
            a.x += acc[ci][0][0]; a.y += acc[ci][0][1]; a.z += acc[ci][0][2]; a.w += acc[ci][0][3];
            b.x += acc[ci][0][4]; b.y += acc[ci][0][5]; b.z += acc[ci][0][6]; b.w += acc[ci][0][7];
            cc.x += acc[ci][1][0]; cc.y += acc[ci][1][1]; cc.z += acc[ci][1][2]; cc.w += acc[ci][1][3];
            d.x += acc[ci][1][4]; d.y += acc[ci][1][5]; d.z += acc[ci][1][6]; d.w += acc[ci][1][7];
            *(float4*)(orow) = a; *(float4*)(orow + 4) = b;
            *(float4*)(orow + 8) = cc; *(float4*)(orow + 12) = d;
        }
    }
}

extern "C" void kernel_launch(void* const* d_in, const int* in_sizes, int n_in,
                              void* d_out, int out_size, void* d_ws, size_t ws_size,
                              hipStream_t stream)
{
    const float* node_feats = (const float*)d_in[1];
    const float* edge_attrs = (const float*)d_in[2];
    const float* edge_feats = (const float*)d_in[3];
    const int*   edge_index = (const int*)d_in[4];
    const float* W_up   = (const float*)d_in[5];
    const float* W_down = (const float*)d_in[6];
    const float* W_skip = (const float*)d_in[7];
    const float* W_fc0  = (const float*)d_in[8];
    const float* W_fc1  = (const float*)d_in[9];
    const float* W_fc2  = (const float*)d_in[10];
    const float* W_fc3  = (const float*)d_in[11];
    const float* W_out  = (const float*)d_in[12];
    const int N = in_sizes[1] / 128;
    const int E = in_sizes[3] / 8;

    float* out = (float*)d_out;
    float* sc  = out + (size_t)N * 2048;

    // workspace layout
    float* xup   = (float*)d_ws;
    float* xdown = xup + (size_t)N * 128;
    int* deg    = (int*)(xdown + (size_t)N * 64);
    int* fill   = deg + N;
    int* rowptr = fill + N;
    int* perm   = rowptr + N + 1;
    size_t used = (size_t)((char*)(perm + E) - (char*)d_ws);
    used = (used + 255) & ~(size_t)255;
    unsigned short* Wt0 = (unsigned short*)((char*)d_ws + used);  // 256 x 160
    unsigned short* Wt1 = Wt0 + 256 * 160;                        // 256 x 256
    unsigned short* Wt2 = Wt1 + 256 * 256;
    unsigned short* Wt3 = Wt2 + 256 * 256;                        // 512 x 256
    unsigned short* WoT = Wt3 + 512 * 256;                        // 4 x 128 x 128
    used = (size_t)((char*)(WoT + 4 * 128 * 128) - (char*)d_ws);
    used = (used + 255) & ~(size_t)255;
    unsigned short* tpw = (unsigned short*)((char*)d_ws + used);  // Ec x 512 (tp_w -> z in place)
    size_t avail = (ws_size > used) ? ws_size - used : 0;
    long long Ec_l = (long long)(avail / (512 * sizeof(unsigned short)));
    int Ec = (int)(Ec_l > E ? E : Ec_l);
    if (Ec < 8) Ec = 8;
    const int nchunks = (E + Ec - 1) / Ec;

    hipMemsetAsync(deg, 0, (size_t)2 * N * sizeof(int), stream);
    if (nchunks > 1)
        hipMemsetAsync(out, 0, (size_t)N * 2048 * sizeof(float), stream);

    dim3 g1((N + 63) / 64, 5);
    k_node_gemm<<<g1, 256, 0, stream>>>(node_feats, W_skip, W_up, W_down, sc, xup, xdown, N);

    constexpr float S0 = 0.085749292571254f; // 1/sqrt(136)
    k_prep_w<<<(256 * 160 + 255) / 256, 256, 0, stream>>>(W_fc0, Wt0, 136, 160, 256, S0);
    k_prep_w<<<(256 * 256 + 255) / 256, 256, 0, stream>>>(W_fc1, Wt1, 256, 256, 256, 0.0625f);
    k_prep_w<<<(256 * 256 + 255) / 256, 256, 0, stream>>>(W_fc2, Wt2, 256, 256, 256, 0.0625f);
    k_prep_w<<<(512 * 256 + 255) / 256, 256, 0, stream>>>(W_fc3, Wt3, 256, 256, 512, 0.0625f);
    for (int l = 0; l < 4; l++)
        k_prep_w<<<(128 * 128 + 255) / 256, 256, 0, stream>>>(W_out + (size_t)l * 16384,
                                                              WoT + (size_t)l * 16384,
                                                              128, 128, 128, 0.1f);

    const int* recv = edge_index + E;
    k_hist<<<(E + 255) / 256, 256, 0, stream>>>(recv, deg, E);
    k_scan<<<1, 1024, 0, stream>>>(deg, rowptr, N);
    k_scatter<<<(E + 255) / 256, 256, 0, stream>>>(recv, rowptr, fill, perm, E);
    k_sortlists<<<(N + 255) / 256, 256, 0, stream>>>(perm, rowptr, N);

    for (int ch = 0; ch < nchunks; ch++) {
        int eLo = ch * Ec;
        int eHi = eLo + Ec; if (eHi > E) eHi = E;
        int nE = eHi - eLo;

        k_mlp_mfma<<<(nE + MEB - 1) / MEB, 512, 0, stream>>>(edge_feats, edge_index, xdown,
                                                             Wt0, Wt1, Wt2, Wt3,
                                                             tpw, E, eLo, eHi);
        k_zx<<<dim3((nE + 127) / 128, 4), 256, 0, stream>>>(tpw, edge_index, xup, WoT,
                                                            E, eLo, eHi);
        k_gather<<<N, 64, 0, stream>>>(tpw, edge_attrs, perm, rowptr,
                                       out, E, eLo, eHi, nchunks == 1 ? 1 : 0);
    }
}

// Round 22
// 327.223 us; speedup vs baseline: 1.1070x; 1.0556x over previous
//
#include <hip/hip_runtime.h>
#include <hip/hip_bf16.h>
#include <math.h>

using bf16x8 = __attribute__((ext_vector_type(8))) short;
using f32x4  = __attribute__((ext_vector_type(4))) float;

__device__ __forceinline__ float silu_f(float x) {
    float e = __expf(-x);
    float d = 1.f + e;
    return x * __builtin_amdgcn_rcpf(d);
}

__device__ __forceinline__ unsigned short f2bf(float x) {
    __hip_bfloat16 h = __float2bfloat16(x);
    return *reinterpret_cast<unsigned short*>(&h);
}
__device__ __forceinline__ unsigned f2bf2(float lo, float hi) {
    __hip_bfloat162 h2 = __float22bfloat162_rn(make_float2(lo, hi));
    return *reinterpret_cast<unsigned*>(&h2);
}
__device__ __forceinline__ float bf2f(unsigned short h) {
    union { unsigned u; float f; } v; v.u = ((unsigned)h) << 16;
    return v.f;
}

// ---------------- K1: node GEMM: sc = A@Wskip, xup = A@Wup, xdown = A@Wdown ----
__global__ __launch_bounds__(256) void k_node_gemm(
    const float* __restrict__ A,
    const float* __restrict__ Wskip, const float* __restrict__ Wup, const float* __restrict__ Wdown,
    float* __restrict__ sc, float* __restrict__ xup, float* __restrict__ xdown, int N)
{
    __shared__ float As[64][129];
    const int t = threadIdx.x;
    const int n0 = blockIdx.x * 64;
    for (int i = t; i < 64 * 32; i += 256) {
        int r = i >> 5, c4 = i & 31;
        int n = n0 + r;
        float4 v = make_float4(0.f, 0.f, 0.f, 0.f);
        if (n < N) v = ((const float4*)(A + (size_t)n * 128))[c4];
        As[r][c4 * 4 + 0] = v.x; As[r][c4 * 4 + 1] = v.y;
        As[r][c4 * 4 + 2] = v.z; As[r][c4 * 4 + 3] = v.w;
    }
    __syncthreads();
    const int tc = t & 15, tr = t >> 4;
    const int col0 = blockIdx.y * 64 + tc * 4;
    const float* W; float* dst; int ldw, wc, ldd;
    if (col0 < 128)      { W = Wskip; ldw = 128; wc = col0;       dst = sc;    ldd = 128; }
    else if (col0 < 256) { W = Wup;   ldw = 128; wc = col0 - 128; dst = xup;   ldd = 128; }
    else                 { W = Wdown; ldw = 64;  wc = col0 - 256; dst = xdown; ldd = 64;  }
    float acc[4][4] = {};
    for (int k = 0; k < 128; k++) {
        float4 wv = *(const float4*)(W + (size_t)k * ldw + wc);
        float wvv[4] = {wv.x, wv.y, wv.z, wv.w};
        float av[4];
        #pragma unroll
        for (int ii = 0; ii < 4; ii++) av[ii] = As[tr * 4 + ii][k];
        #pragma unroll
        for (int ii = 0; ii < 4; ii++)
            #pragma unroll
            for (int jj = 0; jj < 4; jj++)
                acc[ii][jj] = fmaf(av[ii], wvv[jj], acc[ii][jj]);
    }
    #pragma unroll
    for (int ii = 0; ii < 4; ii++) {
        int n = n0 + tr * 4 + ii;
        if (n < N)
            *(float4*)(dst + (size_t)n * ldd + wc) =
                make_float4(acc[ii][0], acc[ii][1], acc[ii][2], acc[ii][3]);
    }
}

// ---------------- k_prep_all: all weight preps + deg/fill zero in one launch ---
// Segments (flat dst, contiguous from Wt0):
//  [0,      40960)  Wt0: W_fc0^T, Kin=136 Kpad=160 Nout=256, scale S0
//  [40960, 106496)  Wt1: W_fc1^T, 256/256/256, 1/16
//  [106496,172032)  Wt2: W_fc2^T, 256/256/256, 1/16
//  [172032,303104)  Wt3: W_fc3^T, 256/256/512, 1/16
//  [303104,368640)  WoT: W_out[l][c][k] -> [l][k][c], 0.1
//  [368640,368640+2N) zero deg+fill (int)
__global__ __launch_bounds__(256) void k_prep_all(
    const float* __restrict__ Wfc0, const float* __restrict__ Wfc1,
    const float* __restrict__ Wfc2, const float* __restrict__ Wfc3,
    const float* __restrict__ Wout,
    unsigned short* __restrict__ WtBase, int* __restrict__ deg2, int N2)
{
    int i = blockIdx.x * 256 + threadIdx.x;
    if (i < 40960) {
        int n = i / 160, k = i - n * 160;
        float v = (k < 136) ? Wfc0[(size_t)k * 256 + n] * 0.085749292571254f : 0.f;
        WtBase[i] = f2bf(v);
    } else if (i < 106496) {
        int lcl = i - 40960;
        int n = lcl >> 8, k = lcl & 255;
        WtBase[i] = f2bf(Wfc1[(size_t)k * 256 + n] * 0.0625f);
    } else if (i < 172032) {
        int lcl = i - 106496;
        int n = lcl >> 8, k = lcl & 255;
        WtBase[i] = f2bf(Wfc2[(size_t)k * 256 + n] * 0.0625f);
    } else if (i < 303104) {
        int lcl = i - 172032;
        int n = lcl >> 8, k = lcl & 255;
        WtBase[i] = f2bf(Wfc3[(size_t)k * 512 + n] * 0.0625f);
    } else if (i < 368640) {
        int lcl = i - 303104;
        int l = lcl >> 14, rem = lcl & 16383;
        int k = rem >> 7, c = rem & 127;
        WtBase[i] = f2bf(Wout[(size_t)l * 16384 + c * 128 + k] * 0.1f);
    } else if (i < 368640 + N2) {
        deg2[i - 368640] = 0;
    }
}

// ---------------- K2: edge MLP via bf16 MFMA -> tp_w (R21 single-buffer) -------
#define MEB 128

__global__ __launch_bounds__(512, 2) void k_mlp_mfma(
    const float* __restrict__ ef, const int* __restrict__ eidx,
    const float* __restrict__ xdown,
    const unsigned short* __restrict__ Wt0, const unsigned short* __restrict__ Wt1,
    const unsigned short* __restrict__ Wt2, const unsigned short* __restrict__ Wt3,
    unsigned short* __restrict__ tp_w, int E, int eLo, int eHi)
{
    __shared__ unsigned short buf[MEB][264];
    __shared__ int sE[MEB], rE[MEB];
    const int t = threadIdx.x;
    const int w = t >> 6, lane = t & 63;
    const int rA = lane & 15;
    const int kb = (lane >> 4) * 8;
    const int r0 = (lane >> 4) * 4;
    const int e0 = eLo + blockIdx.x * MEB;

    bf16x8 bw[16];
    f32x4 acc[8][2];

#define LOADW(WT, KPADW, NKS)                                                     \
    _Pragma("unroll")                                                             \
    for (int ks = 0; ks < NKS; ks++)                                              \
        _Pragma("unroll")                                                         \
        for (int nt = 0; nt < 2; nt++)                                            \
            bw[ks * 2 + nt] = *(const bf16x8*)&(WT)[(size_t)(w * 32 + nt * 16 + rA) * (KPADW) + ks * 32 + kb];

#define LMFMA(IN, NKS)                                                            \
    _Pragma("unroll")                                                             \
    for (int mt = 0; mt < 8; mt++)                                                \
        _Pragma("unroll")                                                         \
        for (int nt = 0; nt < 2; nt++)                                            \
            acc[mt][nt] = (f32x4){0.f, 0.f, 0.f, 0.f};                            \
    _Pragma("unroll")                                                             \
    for (int ks = 0; ks < NKS; ks++) {                                            \
        const int kk = ks * 32 + kb;                                              \
        bf16x8 afr[8];                                                            \
        _Pragma("unroll")                                                         \
        for (int mt = 0; mt < 8; mt++)                                            \
            afr[mt] = *(const bf16x8*)&IN[mt * 16 + rA][kk];                      \
        _Pragma("unroll")                                                         \
        for (int mt = 0; mt < 8; mt++)                                            \
            _Pragma("unroll")                                                     \
            for (int nt = 0; nt < 2; nt++)                                        \
                acc[mt][nt] = __builtin_amdgcn_mfma_f32_16x16x32_bf16(afr[mt], bw[ks * 2 + nt], acc[mt][nt], 0, 0, 0); \
    }

#define EPILOG(OUT, DOSILU)                                                       \
    _Pragma("unroll")                                                             \
    for (int mt = 0; mt < 8; mt++)                                                \
        _Pragma("unroll")                                                         \
        for (int nt = 0; nt < 2; nt++) {                                          \
            const int col = w * 32 + nt * 16 + rA;                                \
            _Pragma("unroll")                                                     \
            for (int r = 0; r < 4; r++) {                                         \
                float x = acc[mt][nt][r];                                         \
                if (DOSILU) x = silu_f(x);                                        \
                OUT[mt * 16 + r0 + r][col] = f2bf(x);                             \
            }                                                                     \
        }

#define STOREG(OFF)                                                               \
    _Pragma("unroll")                                                             \
    for (int mt = 0; mt < 8; mt++) {                                              \
        _Pragma("unroll")                                                         \
        for (int r = 0; r < 4; r++) {                                             \
            int ee = e0 + mt * 16 + r0 + r;                                       \
            if (ee < eHi) {                                                       \
                _Pragma("unroll")                                                 \
                for (int nt = 0; nt < 2; nt++)                                    \
                    tp_w[(size_t)(ee - eLo) * 512 + (OFF) + w * 32 + nt * 16 + rA] = f2bf(acc[mt][nt][r]); \
            }                                                                     \
        }                                                                         \
    }

    if (t < MEB) {
        int e = e0 + t; if (e >= E) e = E - 1;
        sE[t] = eidx[e]; rE[t] = eidx[E + e];
    }
    __syncthreads();
    for (int i = t; i < MEB * 24; i += 512) {
        int r = i / 24, c = 136 + i % 24;
        buf[r][c] = 0;
    }
    for (int i = t; i < MEB * 34; i += 512) {
        int e = i / 34, j = i - e * 34;
        float4 v;
        if (j < 2) { int ee = e0 + e; if (ee >= E) ee = E - 1; v = ((const float4*)(ef + (size_t)ee * 8))[j]; }
        else if (j < 18) v = ((const float4*)(xdown + (size_t)sE[e] * 64))[j - 2];
        else             v = ((const float4*)(xdown + (size_t)rE[e] * 64))[j - 18];
        unsigned lo = f2bf2(v.x, v.y), hi = f2bf2(v.z, v.w);
        *(uint2*)&buf[e][j * 4] = make_uint2(lo, hi);
    }
    __syncthreads();

    LOADW(Wt0, 160, 5)
    LMFMA(buf, 5)
    __syncthreads();
    EPILOG(buf, true)
    __syncthreads();

    LOADW(Wt1, 256, 8)
    LMFMA(buf, 8)
    __syncthreads();
    EPILOG(buf, true)
    __syncthreads();

    LOADW(Wt2, 256, 8)
    LMFMA(buf, 8)
    __syncthreads();
    EPILOG(buf, true)
    __syncthreads();

    LOADW(Wt3, 256, 8)
    LMFMA(buf, 8)
    STOREG(0)

    LOADW(Wt3 + (size_t)256 * 256, 256, 8)
    LMFMA(buf, 8)
    STOREG(256)
#undef LOADW
#undef LMFMA
#undef EPILOG
#undef STOREG
}

// ---------------- k_zx: u = tp_w * xup[sender]; z = u @ WoT[l]^T (in place) ----
__global__ __launch_bounds__(256, 2) void k_zx(
    unsigned short* __restrict__ tpw, const int* __restrict__ eidx,
    const float* __restrict__ xup, const unsigned short* __restrict__ WoT,
    int E, int eLo, int eHi)
{
    __shared__ __align__(16) unsigned short As[128 * 128];
    __shared__ __align__(16) unsigned short Bs[128 * 128];
    const int t = threadIdx.x;
    const int m0 = blockIdx.x * 128;
    const int l  = blockIdx.y;
    const int nE = eHi - eLo;

    #pragma unroll
    for (int i = 0; i < 8; i++) {
        int idx = i * 256 + t;
        int r = idx >> 4, cc = idx & 15;
        int el = m0 + r;
        int ecl = el < nE ? el : nE - 1;
        int s = eidx[eLo + ecl];
        uint4 tv = *(const uint4*)(tpw + (size_t)ecl * 512 + l * 128 + (cc << 3));
        float4 x0 = *(const float4*)(xup + (size_t)s * 128 + (cc << 3));
        float4 x1 = *(const float4*)(xup + (size_t)s * 128 + (cc << 3) + 4);
        const unsigned short* hp = (const unsigned short*)&tv;
        uint4 ov;
        unsigned* op = (unsigned*)&ov;
        op[0] = f2bf2(bf2f(hp[0]) * x0.x, bf2f(hp[1]) * x0.y);
        op[1] = f2bf2(bf2f(hp[2]) * x0.z, bf2f(hp[3]) * x0.w);
        op[2] = f2bf2(bf2f(hp[4]) * x1.x, bf2f(hp[5]) * x1.y);
        op[3] = f2bf2(bf2f(hp[6]) * x1.z, bf2f(hp[7]) * x1.w);
        *(uint4*)(&As[r * 128 + ((cc ^ (r & 7)) << 3)]) = ov;
    }
    #pragma unroll
    for (int i = 0; i < 8; i++) {
        int idx = i * 256 + t;
        int r = idx >> 4, cc = idx & 15;
        uint4 bv = *(const uint4*)(WoT + ((size_t)l * 128 + r) * 128 + (cc << 3));
        *(uint4*)(&Bs[r * 128 + ((cc ^ (r & 7)) << 3)]) = bv;
    }
    __syncthreads();

    const int lane = t & 63, rA = lane & 15, q = lane >> 4;
    const int wm = (t >> 6) & 1, wn = (t >> 6) >> 1;
    f32x4 acc[4][4];
    #pragma unroll
    for (int mt = 0; mt < 4; mt++)
        #pragma unroll
        for (int nt = 0; nt < 4; nt++)
            acc[mt][nt] = (f32x4){0.f, 0.f, 0.f, 0.f};

    #pragma unroll
    for (int ks = 0; ks < 4; ks++) {
        const int cc = ks * 4 + q;
        bf16x8 af[4], bfr[4];
        #pragma unroll
        for (int mt = 0; mt < 4; mt++) {
            int row = wm * 64 + mt * 16 + rA;
            af[mt] = *(const bf16x8*)&As[row * 128 + ((cc ^ (row & 7)) << 3)];
        }
        #pragma unroll
        for (int nt = 0; nt < 4; nt++) {
            int row = wn * 64 + nt * 16 + rA;
            bfr[nt] = *(const bf16x8*)&Bs[row * 128 + ((cc ^ (row & 7)) << 3)];
        }
        #pragma unroll
        for (int mt = 0; mt < 4; mt++)
            #pragma unroll
            for (int nt = 0; nt < 4; nt++)
                acc[mt][nt] = __builtin_amdgcn_mfma_f32_16x16x32_bf16(af[mt], bfr[nt], acc[mt][nt], 0, 0, 0);
    }
    __syncthreads();

    #pragma unroll
    for (int mt = 0; mt < 4; mt++) {
        #pragma unroll
        for (int r = 0; r < 4; r++) {
            int row = m0 + wm * 64 + mt * 16 + q * 4 + r;
            if (row >= nE) continue;
            #pragma unroll
            for (int nt = 0; nt < 4; nt++) {
                int col = wn * 64 + nt * 16 + rA;
                tpw[(size_t)row * 512 + l * 128 + col] = f2bf(acc[mt][nt][r]);
            }
        }
    }
}

// ---------------- CSR construction --------------------------------------------
__global__ __launch_bounds__(256) void k_hist(const int* __restrict__ recv, int* __restrict__ deg, int E)
{
    int e = blockIdx.x * 256 + threadIdx.x;
    if (e < E) atomicAdd(&deg[recv[e]], 1);
}

__global__ __launch_bounds__(1024) void k_scan(const int* __restrict__ deg, int* __restrict__ rowptr, int N)
{
    __shared__ int sdata[1024];
    __shared__ int carry;
    const int t = threadIdx.x;
    if (t == 0) carry = 0;
    __syncthreads();
    for (int base = 0; base < N; base += 1024) {
        int i = base + t;
        int v = (i < N) ? deg[i] : 0;
        sdata[t] = v;
        __syncthreads();
        for (int off = 1; off < 1024; off <<= 1) {
            int x = (t >= off) ? sdata[t - off] : 0;
            __syncthreads();
            sdata[t] += x;
            __syncthreads();
        }
        if (i < N) rowptr[i] = carry + sdata[t] - v;
        __syncthreads();
        if (t == 0) carry += sdata[1023];
        __syncthreads();
    }
    if (t == 0) rowptr[N] = carry;
}

__global__ __launch_bounds__(256) void k_scatter(const int* __restrict__ recv,
    const int* __restrict__ rowptr, int* __restrict__ fill, int* __restrict__ perm, int E)
{
    int e = blockIdx.x * 256 + threadIdx.x;
    if (e < E) {
        int r = recv[e];
        int pos = rowptr[r] + atomicAdd(&fill[r], 1);
        perm[pos] = e;
    }
}

__global__ __launch_bounds__(256) void k_sortlists(int* __restrict__ perm, const int* __restrict__ rowptr, int N)
{
    int n = blockIdx.x * 256 + threadIdx.x;
    if (n >= N) return;
    int lo = rowptr[n], hi = rowptr[n + 1];
    for (int i = lo + 1; i < hi; i++) {
        int key = perm[i];
        int j = i - 1;
        while (j >= lo && perm[j] > key) { perm[j + 1] = perm[j]; j--; }
        perm[j + 1] = key;
    }
}

// ---------------- K3: per-node gather, LDS-staged coalesced z reads (R19) ------
__global__ __launch_bounds__(64) void k_gather(
    const unsigned short* __restrict__ z, const float* __restrict__ ea,
    const int* __restrict__ perm, const int* __restrict__ rowptr,
    float* __restrict__ outb, int E, int eLo, int eHi, int storeMode)
{
    const int n = blockIdx.x;
    const int lo = rowptr[n], hi = rowptr[n + 1];
    const int t = threadIdx.x;
    const int nE = eHi - eLo;
    constexpr float CG1 = 0.57735026919f, CG2 = 0.44721359550f, CG3 = 0.37796447301f;
    float acc[2][2][8] = {};
    __shared__ int eG[64];
    __shared__ int eL[64];
    __shared__ float yL[64][17];
    __shared__ __align__(16) unsigned short zb[4][512];

    const int sle = t >> 4;
    const int sch = t & 15;

    for (int base = lo; base < hi; base += 64) {
        int cnt = min(64, hi - base);
        __syncthreads();
        for (int i = t; i < cnt; i += 64) {
            int e = perm[base + i];
            eG[i] = e;
            int el = e - eLo;
            eL[i] = (el >= 0 && el < nE) ? el : 0;
        }
        __syncthreads();
        for (int i = t; i < cnt * 16; i += 64) {
            int el = i >> 4, m = i & 15;
            int e = eG[el];
            float v = ea[(size_t)e * 16 + m];
            yL[el][m] = (e >= eLo && e < eHi) ? v : 0.f;
        }
        __syncthreads();

        int j = 0;
        for (; j + 4 <= cnt; j += 4) {
            const unsigned short* zz = z + (size_t)eL[j + sle] * 512;
            #pragma unroll
            for (int i = 0; i < 4; i++)
                *(uint4*)&zb[sle][(sch + 16 * i) * 8] = *(const uint4*)(zz + (sch + 16 * i) * 8);
            __syncthreads();
            #pragma unroll
            for (int k = 0; k < 4; k++) {
                const float* y = yL[j + k];
                const unsigned short* zr = zb[k];
                #pragma unroll
                for (int ci = 0; ci < 2; ci++) {
                    int c = t + ci * 64;
                    float z0 = bf2f(zr[c]);
                    float z1 = bf2f(zr[128 + c]) * CG1;
                    float z2 = bf2f(zr[256 + c]) * CG2;
                    float z3 = bf2f(zr[384 + c]) * CG3;
                    acc[ci][0][0] = fmaf(z0, y[0], acc[ci][0][0]);
                    #pragma unroll
                    for (int m = 0; m < 3; m++) acc[ci][0][1 + m] = fmaf(z1, y[1 + m], acc[ci][0][1 + m]);
                    #pragma unroll
                    for (int m = 0; m < 4; m++) acc[ci][0][4 + m] = fmaf(z2, y[4 + m], acc[ci][0][4 + m]);
                    acc[ci][1][0] = fmaf(z2, y[8], acc[ci][1][0]);
                    #pragma unroll
                    for (int m = 0; m < 7; m++) acc[ci][1][1 + m] = fmaf(z3, y[9 + m], acc[ci][1][1 + m]);
                }
            }
            __syncthreads();
        }
        for (; j < cnt; j++) {
            const unsigned short* zz = z + (size_t)eL[j] * 512;
            const float* y = yL[j];
            #pragma unroll
            for (int ci = 0; ci < 2; ci++) {
                int c = t + ci * 64;
                float z0 = bf2f(zz[c]);
                float z1 = bf2f(zz[128 + c]) * CG1;
                float z2 = bf2f(zz[256 + c]) * CG2;
                float z3 = bf2f(zz[384 + c]) * CG3;
                acc[ci][0][0] = fmaf(z0, y[0], acc[ci][0][0]);
                #pragma unroll
                for (int m = 0; m < 3; m++) acc[ci][0][1 + m] = fmaf(z1, y[1 + m], acc[ci][0][1 + m]);
                #pragma unroll
                for (int m = 0; m < 4; m++) acc[ci][0][4 + m] = fmaf(z2, y[4 + m], acc[ci][0][4 + m]);
                acc[ci][1][0] = fmaf(z2, y[8], acc[ci][1][0]);
                #pragma unroll
                for (int m = 0; m < 7; m++) acc[ci][1][1 + m] = fmaf(z3, y[9 + m], acc[ci][1][1 + m]);
            }
        }
    }

    #pragma unroll
    for (int ci = 0; ci < 2; ci++) {
        float* orow = outb + (size_t)n * 2048 + (size_t)(t + ci * 64) * 16;
        if (storeMode) {
            *(float4*)(orow)      = make_float4(acc[ci][0][0], acc[ci][0][1], acc[ci][0][2], acc[ci][0][3]);
            *(float4*)(orow + 4)  = make_float4(acc[ci][0][4], acc[ci][0][5], acc[ci][0][6], acc[ci][0][7]);
            *(float4*)(orow + 8)  = make_float4(acc[ci][1][0], acc[ci][1][1], acc[ci][1][2], acc[ci][1][3]);
            *(float4*)(orow + 12) = make_float4(acc[ci][1][4], acc[ci][1][5], acc[ci][1][6], acc[ci][1][7]);
        } else {
            float4 a = *(float4*)(orow), b = *(float4*)(orow + 4);
            float4 cc = *(float4*)(orow + 8), d = *(float4*)(orow + 12);
            a.x += acc[ci][0][0]; a.y += acc[ci][0][1]; a.z += acc[ci][0][2]; a.w += acc[ci][0][3];
            b.x += acc[ci][0][4]; b.y += acc[ci][0][5]; b.z += acc[ci][0][6]; b.w += acc[ci][0][7];
            cc.x += acc[ci][1][0]; cc.y += acc[ci][1][1]; cc.z += acc[ci][1][2]; cc.w += acc[ci][1][3];
            d.x += acc[ci][1][4]; d.y += acc[ci][1][5]; d.z += acc[ci][1][6]; d.w += acc[ci][1][7];
            *(float4*)(orow) = a; *(float4*)(orow + 4) = b;
            *(float4*)(orow + 8) = cc; *(float4*)(orow + 12) = d;
        }
    }
}

extern "C" void kernel_launch(void* const* d_in, const int* in_sizes, int n_in,
                              void* d_out, int out_size, void* d_ws, size_t ws_size,
                              hipStream_t stream)
{
    const float* node_feats = (const float*)d_in[1];
    const float* edge_attrs = (const float*)d_in[2];
    const float* edge_feats = (const float*)d_in[3];
    const int*   edge_index = (const int*)d_in[4];
    const float* W_up   = (const float*)d_in[5];
    const float* W_down = (const float*)d_in[6];
    const float* W_skip = (const float*)d_in[7];
    const float* W_fc0  = (const float*)d_in[8];
    const float* W_fc1  = (const float*)d_in[9];
    const float* W_fc2  = (const float*)d_in[10];
    const float* W_fc3  = (const float*)d_in[11];
    const float* W_out  = (const float*)d_in[12];
    const int N = in_sizes[1] / 128;
    const int E = in_sizes[3] / 8;

    float* out = (float*)d_out;
    float* sc  = out + (size_t)N * 2048;

    // workspace layout
    float* xup   = (float*)d_ws;
    float* xdown = xup + (size_t)N * 128;
    int* deg    = (int*)(xdown + (size_t)N * 64);
    int* fill   = deg + N;
    int* rowptr = fill + N;
    int* perm   = rowptr + N + 1;
    size_t used = (size_t)((char*)(perm + E) - (char*)d_ws);
    used = (used + 255) & ~(size_t)255;
    unsigned short* Wt0 = (unsigned short*)((char*)d_ws + used);  // 256 x 160
    unsigned short* Wt1 = Wt0 + 256 * 160;                        // 256 x 256
    unsigned short* Wt2 = Wt1 + 256 * 256;
    unsigned short* Wt3 = Wt2 + 256 * 256;                        // 512 x 256
    unsigned short* WoT = Wt3 + 512 * 256;                        // 4 x 128 x 128
    used = (size_t)((char*)(WoT + 4 * 128 * 128) - (char*)d_ws);
    used = (used + 255) & ~(size_t)255;
    unsigned short* tpw = (unsigned short*)((char*)d_ws + used);  // Ec x 512 (tp_w -> z in place)
    size_t avail = (ws_size > used) ? ws_size - used : 0;
    long long Ec_l = (long long)(avail / (512 * sizeof(unsigned short)));
    int Ec = (int)(Ec_l > E ? E : Ec_l);
    if (Ec < 8) Ec = 8;
    const int nchunks = (E + Ec - 1) / Ec;

    if (nchunks > 1)
        hipMemsetAsync(out, 0, (size_t)N * 2048 * sizeof(float), stream);

    // one launch: all weight preps + deg/fill zeroing
    const int prepTotal = 368640 + 2 * N;
    k_prep_all<<<(prepTotal + 255) / 256, 256, 0, stream>>>(W_fc0, W_fc1, W_fc2, W_fc3,
                                                            W_out, Wt0, deg, 2 * N);

    dim3 g1((N + 63) / 64, 5);
    k_node_gemm<<<g1, 256, 0, stream>>>(node_feats, W_skip, W_up, W_down, sc, xup, xdown, N);

    const int* recv = edge_index + E;
    k_hist<<<(E + 255) / 256, 256, 0, stream>>>(recv, deg, E);
    k_scan<<<1, 1024, 0, stream>>>(deg, rowptr, N);
    k_scatter<<<(E + 255) / 256, 256, 0, stream>>>(recv, rowptr, fill, perm, E);
    k_sortlists<<<(N + 255) / 256, 256, 0, stream>>>(perm, rowptr, N);

    for (int ch = 0; ch < nchunks; ch++) {
        int eLo = ch * Ec;
        int eHi = eLo + Ec; if (eHi > E) eHi = E;
        int nE = eHi - eLo;

        k_mlp_mfma<<<(nE + MEB - 1) / MEB, 512, 0, stream>>>(edge_feats, edge_index, xdown,
                                                             Wt0, Wt1, Wt2, Wt3,
                                                             tpw, E, eLo, eHi);
        k_zx<<<dim3((nE + 127) / 128, 4), 256, 0, stream>>>(tpw, edge_index, xup, WoT,
                                                            E, eLo, eHi);
        k_gather<<<N, 64, 0, stream>>>(tpw, edge_attrs, perm, rowptr,
                                       out, E, eLo, eHi, nchunks == 1 ? 1 : 0);
    }
}